// Round 10
// baseline (131.517 us; speedup 1.0000x reference)
//
#include <hip/hip_runtime.h>
#include <hip/hip_cooperative_groups.h>

namespace cg = cooperative_groups;

#define NROWS 8192
#define NBLK  256
// ws layout (bytes) — nothing requires pre-zeroed workspace
#define H_OFF     0         // int h[256][4] (4 KB)
#define IDXNL_OFF 8192      // u16[8192]
#define IDXL_OFF  24576     // u16[8192]
#define P2_OFF    40960     // float partial[256]
#define CSUM_OFF  45056     // float csum[1024]
#define CS_OFF    65536     // float cs[256][1024] (1 MB)
#define XN_OFF    2162688   // bf16 xn[8192][256] (4 MB)

typedef __bf16 bf16x8 __attribute__((ext_vector_type(8)));
typedef float  f32x4  __attribute__((ext_vector_type(4)));

__device__ __forceinline__ unsigned short f2bf(float f) {
  unsigned int u = __float_as_uint(f);
  u += 0x7fffu + ((u >> 16) & 1u);
  return (unsigned short)(u >> 16);
}

__device__ __forceinline__ void gl_lds16(const void* g, void* l) {
  __builtin_amdgcn_global_load_lds(
      (const __attribute__((address_space(1))) unsigned int*)g,
      (__attribute__((address_space(3))) unsigned int*)l, 16, 0, 0);
}

// ---- single cooperative kernel: normalize -> partition -> GEMM-reduce -> final ----
__global__ __launch_bounds__(256, 2) void k_all(const float* __restrict__ x,
                                                const int* __restrict__ tgt,
                                                char* __restrict__ ws,
                                                float* __restrict__ out) {
  __shared__ __align__(16) char sm[65536];   // A: f32 lx[32][256] (32KB); C: 2x32KB dbuf
  __shared__ int lt[32];
  __shared__ int lh[4];
  __shared__ int scnt[4];
  __shared__ int spf;
  __shared__ float wred[8];
  __shared__ float acc8[8];
  __shared__ float dsum_s;

  int* h                = (int*)(ws + H_OFF);
  unsigned short* idxNL = (unsigned short*)(ws + IDXNL_OFF);
  unsigned short* idxL  = (unsigned short*)(ws + IDXL_OFF);
  float* partial        = (float*)(ws + P2_OFF);
  float* csum           = (float*)(ws + CSUM_OFF);
  float* cs             = (float*)(ws + CS_OFF);
  unsigned short* xn    = (unsigned short*)(ws + XN_OFF);
  const char* xnb       = (const char*)xn;

  const int b = blockIdx.x;
  const int tid = threadIdx.x, w = tid >> 6, lane = tid & 63;
  cg::grid_group grid = cg::this_grid();

  // ================= Phase A: normalize 32 rows, hist, class col-sums =================
  {
    float* lx = (float*)sm;   // [32][256]
    if (tid < 32) lt[tid] = tgt[b * 32 + tid];
    if (tid < 4) lh[tid] = 0;
#pragma unroll
    for (int i = 0; i < 8; ++i) {
      int r = w * 8 + i;
      int row = b * 32 + r;
      float4 v = reinterpret_cast<const float4*>(x)[row * 64 + lane];
      float ss = v.x * v.x + v.y * v.y + v.z * v.z + v.w * v.w;
#pragma unroll
      for (int off = 32; off; off >>= 1) ss += __shfl_xor(ss, off);
      float iv = 1.0f / fmaxf(sqrtf(ss), 1e-8f);
      float4 nv = make_float4(v.x * iv, v.y * iv, v.z * iv, v.w * iv);
      ushort4 o;
      o.x = f2bf(nv.x); o.y = f2bf(nv.y); o.z = f2bf(nv.z); o.w = f2bf(nv.w);
      reinterpret_cast<ushort4*>(xn)[row * 64 + lane] = o;
      *reinterpret_cast<float4*>(&lx[r * 256 + lane * 4]) = nv;
    }
    __syncthreads();
    if (tid < 32) atomicAdd(&lh[lt[tid]], 1);
    {
      float m0 = 0, m1 = 0, m2 = 0, m3 = 0;
#pragma unroll
      for (int r = 0; r < 32; ++r) {
        float v = lx[r * 256 + tid];
        int c = lt[r];
        m0 += (c == 0) ? v : 0.0f;
        m1 += (c == 1) ? v : 0.0f;
        m2 += (c == 2) ? v : 0.0f;
        m3 += (c == 3) ? v : 0.0f;
      }
      cs[b * 1024 + tid] = m0;
      cs[b * 1024 + 256 + tid] = m1;
      cs[b * 1024 + 512 + tid] = m2;
      cs[b * 1024 + 768 + tid] = m3;
    }
    __syncthreads();
    if (tid < 4) h[b * 4 + tid] = lh[tid];
  }

  grid.sync();

  // ================= Phase B: global cnt, partition, csum reduction =================
  int L = 0, M = 0, NLc = 0;
  {
    if (tid == 0) spf = 0;
    if (tid < 4) scnt[tid] = 0;
    __syncthreads();
    int c0 = 0, c1 = 0, c2 = 0, c3 = 0;
    const int4* h4 = (const int4*)h;
    for (int i = tid; i < NBLK; i += 256) {
      int4 hv = h4[i];
      c0 += hv.x; c1 += hv.y; c2 += hv.z; c3 += hv.w;
    }
#pragma unroll
    for (int off = 32; off; off >>= 1) {
      c0 += __shfl_xor(c0, off); c1 += __shfl_xor(c1, off);
      c2 += __shfl_xor(c2, off); c3 += __shfl_xor(c3, off);
    }
    if (lane == 0) {
      atomicAdd(&scnt[0], c0); atomicAdd(&scnt[1], c1);
      atomicAdd(&scnt[2], c2); atomicAdd(&scnt[3], c3);
    }
    __syncthreads();
#pragma unroll
    for (int i = 0; i < 4; ++i) if (scnt[i] > 0) L = i;
    NLc = scnt[L];
    M = NROWS - NLc;
    // prefix of L-rows before this block
    int pf = 0;
    for (int i = tid; i < b; i += 256) pf += h[i * 4 + L];
#pragma unroll
    for (int off = 32; off; off >>= 1) pf += __shfl_xor(pf, off);
    if (lane == 0) atomicAdd(&spf, pf);
    __syncthreads();
    int baseL = spf, baseN = b * 32 - spf;
    bool isL = (tid < 32) ? (lt[tid] == L) : false;
    unsigned long long mk = __ballot((tid < 32) && isL);
    if (tid < 32) {
      int pos = __popcll(mk & ((1ull << tid) - 1ull));
      int row = b * 32 + tid;
      if (isL) idxL[baseL + pos] = (unsigned short)row;
      else     idxNL[baseN + (tid - pos)] = (unsigned short)row;
    }
    // csum: this block reduces values 4b..4b+3 across all 256 blocks
#pragma unroll
    for (int vv = 0; vv < 4; ++vv) {
      int v = 4 * b + vv;
      float s = 0.0f;
      for (int i = tid; i < NBLK; i += 256) s += cs[i * 1024 + v];
#pragma unroll
      for (int off = 32; off; off >>= 1) s += __shfl_xor(s, off);
      if (lane == 0) wred[w] = s;
      __syncthreads();
      if (tid == 0) csum[v] = wred[0] + wred[1] + wred[2] + wred[3];
      __syncthreads();
    }
  }

  grid.sync();

  // ================= Phase C: rectangle GEMM-reduce sum relu(c-0.5) =================
  {
    char (*lds)[32768] = (char(*)[32768])sm;
    const int ni = (M + 127) >> 7, nj = (NLc + 127) >> 7;
    const int ntiles = ni * nj;

    const int rl = lane >> 3;
    const unsigned pe = ((unsigned)((lane & 7) ^ rl)) << 4;
    const int wr = (w >> 1) * 64, wc = (w & 1) * 64;
    const int l15 = lane & 15;
    const unsigned q16 = ((unsigned)(lane >> 4)) << 4;
    const unsigned key = ((unsigned)(lane & 7)) << 4;
    const int rowj = (lane >> 4) * 4;

    float bsum = 0.0f;
    for (int t = b; t < ntiles; t += NBLK) {
      int bi = t / nj, bj = t - bi * nj;
      int rm = min(128, M - bi * 128);
      int rn = min(128, NLc - bj * 128);
      bool full = (rm == 128) && (rn == 128);

      unsigned aoff[4], boff[4];
#pragma unroll
      for (int j = 0; j < 4; ++j) {
        int row = (j * 4 + w) * 8 + rl;
        int ga = idxNL[bi * 128 + min(row, rm - 1)];
        int gb = idxL [bj * 128 + min(row, rn - 1)];
        aoff[j] = (unsigned)ga * 512u + pe;
        boff[j] = (unsigned)gb * 512u + pe;
      }

      auto stage = [&](int buf, int ch) {
        unsigned cbo = (unsigned)(ch << 7);
#pragma unroll
        for (int j = 0; j < 4; ++j)
          gl_lds16(xnb + (size_t)(aoff[j] + cbo), &lds[buf][(j * 4 + w) * 1024]);
#pragma unroll
        for (int j = 0; j < 4; ++j)
          gl_lds16(xnb + (size_t)(boff[j] + cbo), &lds[buf][16384 + (j * 4 + w) * 1024]);
      };

      f32x4 acc[4][4];
#pragma unroll
      for (int m = 0; m < 4; ++m)
#pragma unroll
        for (int n = 0; n < 4; ++n)
          acc[m][n] = (f32x4){0.f, 0.f, 0.f, 0.f};

      auto compute = [&](int buf) {
        const char* bA = lds[buf];
        const char* bB = lds[buf] + 16384;
#pragma unroll
        for (int ks = 0; ks < 2; ++ks) {
          const unsigned q = (unsigned)(ks * 64) + q16;
          bf16x8 af[4], bfr[4];
#pragma unroll
          for (int m = 0; m < 4; ++m)
            af[m] = *(const bf16x8*)(bA + (wr + m * 16 + l15) * 128 + (q ^ key));
#pragma unroll
          for (int n = 0; n < 4; ++n)
            bfr[n] = *(const bf16x8*)(bB + (wc + n * 16 + l15) * 128 + (q ^ key));
          __builtin_amdgcn_s_setprio(1);
#pragma unroll
          for (int m = 0; m < 4; ++m)
#pragma unroll
            for (int n = 0; n < 4; ++n)
              acc[m][n] = __builtin_amdgcn_mfma_f32_16x16x32_bf16(af[m], bfr[n], acc[m][n], 0, 0, 0);
          __builtin_amdgcn_s_setprio(0);
        }
      };

      __syncthreads();
      stage(0, 0); stage(1, 1);
      asm volatile("s_waitcnt vmcnt(8)" ::: "memory");
      __builtin_amdgcn_s_barrier();
      compute(0);
      __builtin_amdgcn_s_barrier();
      stage(0, 2);
      asm volatile("s_waitcnt vmcnt(8)" ::: "memory");
      __builtin_amdgcn_s_barrier();
      compute(1);
      __builtin_amdgcn_s_barrier();
      stage(1, 3);
      asm volatile("s_waitcnt vmcnt(8)" ::: "memory");
      __builtin_amdgcn_s_barrier();
      compute(0);
      __builtin_amdgcn_s_barrier();
      asm volatile("s_waitcnt vmcnt(0)" ::: "memory");
      __builtin_amdgcn_s_barrier();
      compute(1);

      if (full) {
#pragma unroll
        for (int m = 0; m < 4; ++m)
#pragma unroll
          for (int n = 0; n < 4; ++n)
#pragma unroll
            for (int j = 0; j < 4; ++j)
              bsum += fmaxf(acc[m][n][j] - 0.5f, 0.0f);
      } else {
#pragma unroll
        for (int m = 0; m < 4; ++m) {
#pragma unroll
          for (int j = 0; j < 4; ++j) {
            bool rv = (wr + m * 16 + rowj + j) < rm;
#pragma unroll
            for (int n = 0; n < 4; ++n) {
              bool cv = (wc + n * 16 + l15) < rn;
              float g = fmaxf(acc[m][n][j] - 0.5f, 0.0f);
              bsum += (rv && cv) ? g : 0.0f;
            }
          }
        }
      }
    }

#pragma unroll
    for (int off = 32; off; off >>= 1) bsum += __shfl_xor(bsum, off);
    if (lane == 0) wred[w] = bsum;
    __syncthreads();
    if (tid == 0) partial[b] = wred[0] + wred[1] + wred[2] + wred[3];
  }

  grid.sync();

  // ================= Phase D: block 0 final reduce + closed form =================
  if (b == 0) {
    float s = partial[tid];
#pragma unroll
    for (int off = 32; off; off >>= 1) s += __shfl_xor(s, off);
    if (lane == 0) wred[w] = s;
    __syncthreads();
    if (tid == 0) dsum_s = wred[0] + wred[1] + wred[2] + wred[3];
    __syncthreads();

    float m0 = csum[tid], m1 = csum[256 + tid], m2 = csum[512 + tid], m3 = csum[768 + tid];
    float T = m0 + m1 + m2 + m3;
    float vals[8];
    vals[0] = m0 * m0; vals[1] = m1 * m1; vals[2] = m2 * m2; vals[3] = m3 * m3;
    vals[4] = (T - m0) * (T - m0); vals[5] = (T - m1) * (T - m1);
    vals[6] = (T - m2) * (T - m2); vals[7] = (T - m3) * (T - m3);
#pragma unroll
    for (int v = 0; v < 8; ++v) {
      float sv = vals[v];
#pragma unroll
      for (int off = 32; off; off >>= 1) sv += __shfl_xor(sv, off);
      if (lane == 0) wred[w] = sv;
      __syncthreads();
      if (tid == 0) acc8[v] = wred[0] + wred[1] + wred[2] + wred[3];
      __syncthreads();
    }
    if (tid == 0) {
      double dsum = (double)dsum_s;
      double D = (double)NROWS;   // sum of |unit vector|^2
      double same = 0.0;
#pragma unroll
      for (int i = 0; i < 4; ++i) {
        int k = scnt[i];
        if (k > 0) {
          double Pi = 0.5 * (double)k * (double)(k - 1)
                    + 0.5 * (double)(NROWS - k) * (double)(NROWS - k - 1);
          double Si = 0.5 * ((double)acc8[i] + (double)acc8[4 + i] - D);
          same += (Pi - Si) / (double)k;
        }
      }
      out[0] = (float)((same + dsum) / (double)NROWS);
    }
  }
}

extern "C" void kernel_launch(void* const* d_in, const int* in_sizes, int n_in,
                              void* d_out, int out_size, void* d_ws, size_t ws_size,
                              hipStream_t stream) {
  (void)in_sizes; (void)n_in; (void)out_size; (void)ws_size;
  const float* x  = (const float*)d_in[0];
  const int* tgt  = (const int*)d_in[1];
  float* out      = (float*)d_out;
  char* ws        = (char*)d_ws;

  void* args[] = { (void*)&x, (void*)&tgt, (void*)&ws, (void*)&out };
  (void)hipLaunchCooperativeKernel(reinterpret_cast<const void*>(&k_all),
                                   dim3(NBLK), dim3(256), args, 0, stream);
}

// Round 11
// 89.600 us; speedup vs baseline: 1.4678x; 1.4678x over previous
//
#include <hip/hip_runtime.h>

#define NROWS 8192
#define NBM   512          // k_main blocks
// ws layout (bytes) — nothing requires pre-zeroed workspace
#define H_OFF    0         // int h[128][4] (2 KB)        (k_norm)
#define DONE_OFF 4096      // unsigned done               (k_norm zeroes)
#define P2_OFF   8192      // float partial[NBM]          (k_main)
#define CS_OFF   65536     // float cs[128][1024] (512 KB)(k_norm)
#define XN_OFF   1048576   // bf16 xn[8192][256] (4 MB)   (k_norm)

typedef __bf16 bf16x8 __attribute__((ext_vector_type(8)));
typedef float  f32x4  __attribute__((ext_vector_type(4)));

__device__ __forceinline__ unsigned short f2bf(float f) {
  unsigned int u = __float_as_uint(f);
  u += 0x7fffu + ((u >> 16) & 1u);
  return (unsigned short)(u >> 16);
}

__device__ __forceinline__ void gl_lds16(const void* g, void* l) {
  __builtin_amdgcn_global_load_lds(
      (const __attribute__((address_space(1))) unsigned int*)g,
      (__attribute__((address_space(3))) unsigned int*)l, 16, 0, 0);
}

// ---- normalize + bf16 + per-64-row-chunk class hist + class column-sums ----
// 128 blocks x 1024 threads, 64 rows/block (proven R7 kernel + done-counter zero)
__global__ __launch_bounds__(1024) void k_norm(const float* __restrict__ x,
                                               const int* __restrict__ tgt,
                                               unsigned short* __restrict__ xn,
                                               int* __restrict__ h,
                                               float* __restrict__ cs,
                                               unsigned* __restrict__ done) {
  __shared__ float lx[64][256];    // 64 KB
  __shared__ int lt[64];
  __shared__ int lh[4];
  const int tid = threadIdx.x, w = tid >> 6, lane = tid & 63;
  const int b = blockIdx.x;
  if (b == 0 && tid == 0) *done = 0;
  if (tid < 4) lh[tid] = 0;
  if (tid < 64) lt[tid] = tgt[b * 64 + tid];
#pragma unroll
  for (int i = 0; i < 4; ++i) {
    int r = w * 4 + i;
    int row = b * 64 + r;
    float4 v = reinterpret_cast<const float4*>(x)[row * 64 + lane];
    float ss = v.x * v.x + v.y * v.y + v.z * v.z + v.w * v.w;
#pragma unroll
    for (int off = 32; off; off >>= 1) ss += __shfl_xor(ss, off);
    float iv = 1.0f / fmaxf(sqrtf(ss), 1e-8f);
    float4 nv = make_float4(v.x * iv, v.y * iv, v.z * iv, v.w * iv);
    ushort4 o;
    o.x = f2bf(nv.x); o.y = f2bf(nv.y); o.z = f2bf(nv.z); o.w = f2bf(nv.w);
    reinterpret_cast<ushort4*>(xn)[row * 64 + lane] = o;
    *reinterpret_cast<float4*>(&lx[r][lane * 4]) = nv;
  }
  __syncthreads();
  if (tid < 64) atomicAdd(&lh[lt[tid]], 1);
  {
    const int c = tid >> 8, col = tid & 255;
    float m = 0.0f;
#pragma unroll 8
    for (int r = 0; r < 64; ++r)
      m += (lt[r] == c) ? lx[r][col] : 0.0f;
    cs[b * 1024 + tid] = m;
  }
  __syncthreads();
  if (tid < 4) h[b * 4 + tid] = lh[tid];
}

// ---- rectangle GEMM-reduce + in-block gather-list build + last-block final ----
__global__ __launch_bounds__(256, 2) void k_main(const char* __restrict__ xnb,
                                                 const int* __restrict__ tgt,
                                                 const int* __restrict__ h,
                                                 const float* __restrict__ cs,
                                                 unsigned* __restrict__ done,
                                                 float* __restrict__ partial,
                                                 float* __restrict__ out) {
  __shared__ __align__(16) char sm[65536];     // 2x32KB dbuf
  __shared__ unsigned short hN[128], hL[128];
  __shared__ unsigned short PN[129], PL[129];  // exclusive chunk prefixes
  __shared__ unsigned short lsA[128], lsB[128];
  __shared__ int scnt[4];
  __shared__ float wred[8];
  __shared__ unsigned sold;
  __shared__ float dsum_s;
  __shared__ float acc8[8];

  const int b = blockIdx.x;
  const int tid = threadIdx.x, w = tid >> 6, lane = tid & 63;

  // ---- global cnt from h ----
  if (tid < 4) scnt[tid] = 0;
  __syncthreads();
  {
    int c0 = 0, c1 = 0, c2 = 0, c3 = 0;
    if (tid < 128) { int4 hv = ((const int4*)h)[tid]; c0 = hv.x; c1 = hv.y; c2 = hv.z; c3 = hv.w; }
#pragma unroll
    for (int off = 32; off; off >>= 1) {
      c0 += __shfl_xor(c0, off); c1 += __shfl_xor(c1, off);
      c2 += __shfl_xor(c2, off); c3 += __shfl_xor(c3, off);
    }
    if (lane == 0) {
      atomicAdd(&scnt[0], c0); atomicAdd(&scnt[1], c1);
      atomicAdd(&scnt[2], c2); atomicAdd(&scnt[3], c3);
    }
  }
  __syncthreads();
  int L = 0;
#pragma unroll
  for (int i = 0; i < 4; ++i) if (scnt[i] > 0) L = i;
  const int NL = scnt[L], M = NROWS - NL;
  const int ni = (M + 127) >> 7, nj = (NL + 127) >> 7;
  const int ntiles = ni * nj;

  // ---- chunk counts + exclusive prefix (Hillis-Steele, 128 entries) ----
  if (tid < 128) {
    int hl = h[tid * 4 + L];
    hL[tid] = (unsigned short)hl;
    hN[tid] = (unsigned short)(64 - hl);
    PL[tid + 1] = (unsigned short)hl;
    PN[tid + 1] = (unsigned short)(64 - hl);
  }
  if (tid == 0) { PN[0] = 0; PL[0] = 0; }
  __syncthreads();
  for (int ofs = 1; ofs < 128; ofs <<= 1) {
    unsigned short vn = 0, vl = 0;
    int i = tid + 1;
    bool act = (tid < 128) && (i > ofs);
    if (act) { vn = PN[i - ofs]; vl = PL[i - ofs]; }
    __syncthreads();
    if (act) { PN[i] += vn; PL[i] += vl; }
    __syncthreads();
  }

  // ---- GEMM geometry (verified R7 scheme) ----
  const int rl = lane >> 3;
  const unsigned pe = ((unsigned)((lane & 7) ^ rl)) << 4;
  const int wr = (w >> 1) * 64, wc = (w & 1) * 64;
  const int l15 = lane & 15;
  const unsigned q16 = ((unsigned)(lane >> 4)) << 4;
  const unsigned key = ((unsigned)(lane & 7)) << 4;
  const int rowj = (lane >> 4) * 4;
  char (*lds)[32768] = (char(*)[32768])sm;

  float bsum = 0.0f;
  for (int t = b; t < ntiles; t += NBM) {
    int bi = t / nj, bj = t - bi * nj;
    int rm = min(128, M - bi * 128);
    int rn = min(128, NL - bj * 128);
    bool full = (rm == 128) && (rn == 128);

    // build gather lists for this tile (disjoint writes; one barrier)
    if (tid < 128) {
      if (tid >= rm) lsA[tid] = 0;
      if (tid >= rn) lsB[tid] = 0;
    }
    for (int c = w; c < 128; c += 4) {
      bool needA = (PN[c] < bi * 128 + rm) && (PN[c] + hN[c] > bi * 128);
      bool needB = (PL[c] < bj * 128 + rn) && (PL[c] + hL[c] > bj * 128);
      if (needA || needB) {
        int tv = tgt[c * 64 + lane];
        bool isL = (tv == L);
        unsigned long long mk = __ballot(isL);
        int rkL = __popcll(mk & ((1ull << lane) - 1ull));
        if (isL) {
          int rel = PL[c] + rkL - bj * 128;
          if (rel >= 0 && rel < rn) lsB[rel] = (unsigned short)(c * 64 + lane);
        } else {
          int rel = PN[c] + (lane - rkL) - bi * 128;
          if (rel >= 0 && rel < rm) lsA[rel] = (unsigned short)(c * 64 + lane);
        }
      }
    }
    __syncthreads();

    unsigned aoff[4], boff[4];
#pragma unroll
    for (int j = 0; j < 4; ++j) {
      int row = (j * 4 + w) * 8 + rl;
      aoff[j] = (unsigned)lsA[row] * 512u + pe;
      boff[j] = (unsigned)lsB[row] * 512u + pe;
    }

    auto stage = [&](int buf, int ch) {
      unsigned cbo = (unsigned)(ch << 7);
#pragma unroll
      for (int j = 0; j < 4; ++j)
        gl_lds16(xnb + (size_t)(aoff[j] + cbo), &lds[buf][(j * 4 + w) * 1024]);
#pragma unroll
      for (int j = 0; j < 4; ++j)
        gl_lds16(xnb + (size_t)(boff[j] + cbo), &lds[buf][16384 + (j * 4 + w) * 1024]);
    };

    f32x4 acc[4][4];
#pragma unroll
    for (int m = 0; m < 4; ++m)
#pragma unroll
      for (int n = 0; n < 4; ++n)
        acc[m][n] = (f32x4){0.f, 0.f, 0.f, 0.f};

    auto compute = [&](int buf) {
      const char* bA = lds[buf];
      const char* bB = lds[buf] + 16384;
#pragma unroll
      for (int ks = 0; ks < 2; ++ks) {
        const unsigned q = (unsigned)(ks * 64) + q16;
        bf16x8 af[4], bfr[4];
#pragma unroll
        for (int m = 0; m < 4; ++m)
          af[m] = *(const bf16x8*)(bA + (wr + m * 16 + l15) * 128 + (q ^ key));
#pragma unroll
        for (int n = 0; n < 4; ++n)
          bfr[n] = *(const bf16x8*)(bB + (wc + n * 16 + l15) * 128 + (q ^ key));
        __builtin_amdgcn_s_setprio(1);
#pragma unroll
        for (int m = 0; m < 4; ++m)
#pragma unroll
          for (int n = 0; n < 4; ++n)
            acc[m][n] = __builtin_amdgcn_mfma_f32_16x16x32_bf16(af[m], bfr[n], acc[m][n], 0, 0, 0);
        __builtin_amdgcn_s_setprio(0);
      }
    };

    stage(0, 0); stage(1, 1);
    asm volatile("s_waitcnt vmcnt(8)" ::: "memory");
    __builtin_amdgcn_s_barrier();
    compute(0);
    __builtin_amdgcn_s_barrier();
    stage(0, 2);
    asm volatile("s_waitcnt vmcnt(8)" ::: "memory");
    __builtin_amdgcn_s_barrier();
    compute(1);
    __builtin_amdgcn_s_barrier();
    stage(1, 3);
    asm volatile("s_waitcnt vmcnt(8)" ::: "memory");
    __builtin_amdgcn_s_barrier();
    compute(0);
    __builtin_amdgcn_s_barrier();
    asm volatile("s_waitcnt vmcnt(0)" ::: "memory");
    __builtin_amdgcn_s_barrier();
    compute(1);

    if (full) {
#pragma unroll
      for (int m = 0; m < 4; ++m)
#pragma unroll
        for (int n = 0; n < 4; ++n)
#pragma unroll
          for (int j = 0; j < 4; ++j)
            bsum += fmaxf(acc[m][n][j] - 0.5f, 0.0f);
    } else {
#pragma unroll
      for (int m = 0; m < 4; ++m) {
#pragma unroll
        for (int j = 0; j < 4; ++j) {
          bool rv = (wr + m * 16 + rowj + j) < rm;
#pragma unroll
          for (int n = 0; n < 4; ++n) {
            bool cv = (wc + n * 16 + l15) < rn;
            float g = fmaxf(acc[m][n][j] - 0.5f, 0.0f);
            bsum += (rv && cv) ? g : 0.0f;
          }
        }
      }
    }
    __syncthreads();   // protect lsA/lsB + dbuf for next tile
  }

  // ---- per-block partial, then last-arriving block finishes ----
#pragma unroll
  for (int off = 32; off; off >>= 1) bsum += __shfl_xor(bsum, off);
  if (lane == 0) wred[w] = bsum;
  __syncthreads();
  if (tid == 0) partial[b] = wred[0] + wred[1] + wred[2] + wred[3];
  __threadfence();
  if (tid == 0) sold = atomicAdd(done, 1u);
  __syncthreads();
  if (sold != NBM - 1) return;

  // ---- final phase (one block; values deterministic) ----
  __threadfence();
  {
    float s = partial[tid] + partial[tid + 256];
#pragma unroll
    for (int off = 32; off; off >>= 1) s += __shfl_xor(s, off);
    if (lane == 0) wred[w] = s;
    __syncthreads();
    if (tid == 0) dsum_s = wred[0] + wred[1] + wred[2] + wred[3];
    __syncthreads();

    float m0 = 0, m1 = 0, m2 = 0, m3 = 0;
    for (int bb = 0; bb < 128; ++bb) {
      const float* p = cs + bb * 1024;
      m0 += p[tid]; m1 += p[256 + tid]; m2 += p[512 + tid]; m3 += p[768 + tid];
    }
    float T = m0 + m1 + m2 + m3;
    float vals[8];
    vals[0] = m0 * m0; vals[1] = m1 * m1; vals[2] = m2 * m2; vals[3] = m3 * m3;
    vals[4] = (T - m0) * (T - m0); vals[5] = (T - m1) * (T - m1);
    vals[6] = (T - m2) * (T - m2); vals[7] = (T - m3) * (T - m3);
#pragma unroll
    for (int v = 0; v < 8; ++v) {
      float sv = vals[v];
#pragma unroll
      for (int off = 32; off; off >>= 1) sv += __shfl_xor(sv, off);
      if (lane == 0) wred[w] = sv;
      __syncthreads();
      if (tid == 0) acc8[v] = wred[0] + wred[1] + wred[2] + wred[3];
      __syncthreads();
    }
    if (tid == 0) {
      double dsum = (double)dsum_s;
      double D = (double)NROWS;   // sum of |unit vector|^2
      double same = 0.0;
#pragma unroll
      for (int i = 0; i < 4; ++i) {
        int k = scnt[i];
        if (k > 0) {
          double Pi = 0.5 * (double)k * (double)(k - 1)
                    + 0.5 * (double)(NROWS - k) * (double)(NROWS - k - 1);
          double Si = 0.5 * ((double)acc8[i] + (double)acc8[4 + i] - D);
          same += (Pi - Si) / (double)k;
        }
      }
      out[0] = (float)((same + dsum) / (double)NROWS);
    }
  }
}

extern "C" void kernel_launch(void* const* d_in, const int* in_sizes, int n_in,
                              void* d_out, int out_size, void* d_ws, size_t ws_size,
                              hipStream_t stream) {
  (void)in_sizes; (void)n_in; (void)out_size; (void)ws_size;
  const float* x  = (const float*)d_in[0];
  const int* tgt  = (const int*)d_in[1];
  float* out      = (float*)d_out;
  char* ws        = (char*)d_ws;

  int* h          = (int*)(ws + H_OFF);
  unsigned* done  = (unsigned*)(ws + DONE_OFF);
  float* partial  = (float*)(ws + P2_OFF);
  float* cs       = (float*)(ws + CS_OFF);
  unsigned short* xn = (unsigned short*)(ws + XN_OFF);

  k_norm<<<128, 1024, 0, stream>>>(x, tgt, xn, h, cs, done);
  k_main<<<NBM, 256, 0, stream>>>((const char*)xn, tgt, h, cs, done, partial, out);
}